// Round 4
// baseline (89.154 us; speedup 1.0000x reference)
//
#include <hip/hip_runtime.h>
#include <math.h>

#define BATCH 64
#define NV 1024
#define NL 512
#define DIM 512
#define TMM 128
#define TNN 128
#define BK 32
#define NKT (DIM / BK)   // 16 K-iterations

typedef __bf16 bf16x8 __attribute__((ext_vector_type(8)));
typedef __bf16 bf16x4 __attribute__((ext_vector_type(4)));
typedef float f32x4 __attribute__((ext_vector_type(4)));

// Raw barrier: drain LDS ops only; global loads stay in flight (T4).
#define BARRIER() do { \
    asm volatile("s_waitcnt lgkmcnt(0)" ::: "memory"); \
    __builtin_amdgcn_s_barrier(); \
} while (0)

// =====================================================================
// Fused kernel: fp32 load -> (norms, bf16 convert) -> LDS -> MFMA GEMM
// -> distance epilogue -> row/col min partials.
// grid = 2048 (XCD-swizzled to (b, mt, nt)), block = 256 (4 waves 2x2).
// Pipeline: tile t staged in regset (t&1); loads issued 2 tiles ahead,
// consumed 1 tile later -> counted vmcnt, never 0 in the loop.
// =====================================================================
__global__ __launch_bounds__(256, 3) void fused_distmin_kernel(
    const float* __restrict__ video, const float* __restrict__ lang,
    float* __restrict__ rowpart, float* __restrict__ colpart) {
    // Octet-major LDS: slab o in [0,4) holds k = [o*8, o*8+8) for all rows,
    // 16B per (o,row) entry. Reads (b128) and writes (b64) are bank-even.
    __shared__ __align__(16) ushort AsU[2][4][TMM][8];  // 16 KB
    __shared__ __align__(16) ushort BsU[2][4][TNN][8];  // 16 KB
    __shared__ float anrm[TMM], bnrm[TNN];
    __shared__ float rowred[2][TMM], colred[2][TNN];

    // XCD-aware bijective swizzle: nwg = 2048 = 8 * 256.
    const int wg = ((blockIdx.x & 7) << 8) | (blockIdx.x >> 3);
    const int b = wg >> 5;          // 64 batches
    const int r5 = wg & 31;
    const int mt = r5 >> 2;         // 8 video row-blocks
    const int nt = r5 & 3;          // 4 lang col-blocks

    const int tid = threadIdx.x;
    const int lane = tid & 63;
    const int w = tid >> 6;
    const int wrow = w >> 1;        // 0..1
    const int wcol = w & 1;         // 0..1
    const int lr = lane & 15;
    const int g = lane >> 4;        // k-octet for fragment reads

    // staging geometry: thread owns rows {srow+32t}, k-quad skq (4 floats)
    const int srow = tid >> 3;      // 0..31
    const int skq = tid & 7;        // 0..7
    const int o_sl = skq >> 1;      // slab
    const int half = skq & 1;       // 8B half of the 16B entry

    const float* Ath = video + ((size_t)b * NV + (size_t)mt * TMM + srow) * DIM + skq * 4;
    const float* Bth = lang + ((size_t)b * NL + (size_t)nt * TNN + srow) * DIM + skq * 4;

    float nA[4] = {0.f, 0.f, 0.f, 0.f};
    float nB[4] = {0.f, 0.f, 0.f, 0.f};

    f32x4 acc[4][4];
#pragma unroll
    for (int i = 0; i < 4; i++)
#pragma unroll
        for (int j = 0; j < 4; j++) acc[i][j] = (f32x4){0.f, 0.f, 0.f, 0.f};

    float4 va0[4], vb0[4], va1[4], vb1[4];

#define LOADSET(S, K0)                                                         \
    {                                                                          \
        _Pragma("unroll") for (int t = 0; t < 4; ++t) {                        \
            va##S[t] = *(const float4*)(Ath + (size_t)t * 32 * DIM + (K0));    \
            vb##S[t] = *(const float4*)(Bth + (size_t)t * 32 * DIM + (K0));    \
        }                                                                      \
    }

#define WRITESET(S)                                                            \
    {                                                                          \
        _Pragma("unroll") for (int t = 0; t < 4; ++t) {                        \
            float4 v = va##S[t];                                               \
            nA[t] += v.x * v.x + v.y * v.y + v.z * v.z + v.w * v.w;            \
            bf16x4 p = {(__bf16)v.x, (__bf16)v.y, (__bf16)v.z, (__bf16)v.w};   \
            *(bf16x4*)&AsU[S][o_sl][srow + 32 * t][half * 4] = p;              \
            float4 u = vb##S[t];                                               \
            nB[t] += u.x * u.x + u.y * u.y + u.z * u.z + u.w * u.w;            \
            bf16x4 q = {(__bf16)u.x, (__bf16)u.y, (__bf16)u.z, (__bf16)u.w};   \
            *(bf16x4*)&BsU[S][o_sl][srow + 32 * t][half * 4] = q;              \
        }                                                                      \
    }

#define MFMA_PHASE(C)                                                          \
    {                                                                          \
        bf16x8 av[4], bv[4];                                                   \
        _Pragma("unroll") for (int fr = 0; fr < 4; ++fr)                       \
            av[fr] = *(const bf16x8*)&AsU[C][g][wrow * 64 + fr * 16 + lr][0];  \
        _Pragma("unroll") for (int fc = 0; fc < 4; ++fc)                       \
            bv[fc] = *(const bf16x8*)&BsU[C][g][wcol * 64 + fc * 16 + lr][0];  \
        _Pragma("unroll") for (int fr = 0; fr < 4; ++fr)                       \
            _Pragma("unroll") for (int fc = 0; fc < 4; ++fc)                   \
                acc[fr][fc] = __builtin_amdgcn_mfma_f32_16x16x32_bf16(         \
                    av[fr], bv[fc], acc[fr][fc], 0, 0, 0);                     \
    }

    // prologue: tiles 0 and 1 in flight; buf0 <- tile0
    LOADSET(0, 0);
    LOADSET(1, BK);
    WRITESET(0);
    BARRIER();

    // main loop: iter kt does {load tile kt+2, MFMA tile kt, write tile kt+1}
#pragma unroll 1
    for (int kt = 0; kt < NKT - 2; kt += 2) {
        LOADSET(0, (kt + 2) * BK);
        MFMA_PHASE(0);
        WRITESET(1);
        BARRIER();
        LOADSET(1, (kt + 3) * BK);
        MFMA_PHASE(1);
        WRITESET(0);
        BARRIER();
    }
    // kt = 14: MFMA tile14, write tile15
    MFMA_PHASE(0);
    WRITESET(1);
    BARRIER();
    // kt = 15: MFMA tile15 (no more staging)
    MFMA_PHASE(1);

    // ---- norms: reduce partials across the 8 threads sharing each row ----
#pragma unroll
    for (int t = 0; t < 4; ++t) {
#pragma unroll
        for (int s = 1; s < 8; s <<= 1) {
            nA[t] += __shfl_xor(nA[t], s);
            nB[t] += __shfl_xor(nB[t], s);
        }
    }
    if ((tid & 7) == 0) {
#pragma unroll
        for (int t = 0; t < 4; ++t) {
            anrm[srow + 32 * t] = nA[t];
            bnrm[srow + 32 * t] = nB[t];
        }
    }
    __syncthreads();

    // ---- epilogue: d = |v|^2 - 2 dot + |l|^2, row/col mins ----
    const int rgrp = (lane >> 4) * 4;
    float anorm[4][4];
#pragma unroll
    for (int fr = 0; fr < 4; ++fr)
#pragma unroll
        for (int r = 0; r < 4; ++r)
            anorm[fr][r] = anrm[wrow * 64 + fr * 16 + rgrp + r];
    float bnorm[4];
#pragma unroll
    for (int fc = 0; fc < 4; ++fc)
        bnorm[fc] = bnrm[wcol * 64 + fc * 16 + lr];

    float rmin[4][4];
    float cmin[4];
#pragma unroll
    for (int fr = 0; fr < 4; ++fr)
#pragma unroll
        for (int r = 0; r < 4; ++r) rmin[fr][r] = INFINITY;
#pragma unroll
    for (int fc = 0; fc < 4; ++fc) cmin[fc] = INFINITY;

#pragma unroll
    for (int fr = 0; fr < 4; ++fr)
#pragma unroll
        for (int fc = 0; fc < 4; ++fc)
#pragma unroll
            for (int r = 0; r < 4; ++r) {
                float d = anorm[fr][r] - 2.0f * acc[fr][fc][r] + bnorm[fc];
                rmin[fr][r] = fminf(rmin[fr][r], d);
                cmin[fc] = fminf(cmin[fc], d);
            }

#pragma unroll
    for (int fr = 0; fr < 4; ++fr)
#pragma unroll
        for (int r = 0; r < 4; ++r) {
#pragma unroll
            for (int off = 1; off < 16; off <<= 1)
                rmin[fr][r] = fminf(rmin[fr][r], __shfl_xor(rmin[fr][r], off));
        }
#pragma unroll
    for (int fc = 0; fc < 4; ++fc) {
#pragma unroll
        for (int off = 16; off < 64; off <<= 1)
            cmin[fc] = fminf(cmin[fc], __shfl_xor(cmin[fc], off));
    }

    if ((lane & 15) == 0) {
#pragma unroll
        for (int fr = 0; fr < 4; ++fr)
#pragma unroll
            for (int r = 0; r < 4; ++r)
                rowred[wcol][wrow * 64 + fr * 16 + rgrp + r] = rmin[fr][r];
    }
    if (lane < 16) {
#pragma unroll
        for (int fc = 0; fc < 4; ++fc)
            colred[wrow][wcol * 64 + fc * 16 + lane] = cmin[fc];
    }
    __syncthreads();
    if (tid < TMM) {
        rowpart[((size_t)(b * 4 + nt)) * NV + mt * TMM + tid] =
            fminf(rowred[0][tid], rowred[1][tid]);
    } else {
        int c2 = tid - TMM;
        colpart[((size_t)(b * 8 + mt)) * NL + nt * TNN + c2] =
            fminf(colred[0][c2], colred[1][c2]);
    }
}

// ---------------- final reduce ----------------------------------------------
__global__ __launch_bounds__(256) void reduce2_kernel(
    const float* __restrict__ rowpart, const float* __restrict__ colpart,
    float* __restrict__ out) {
    int b = blockIdx.x;
    int tid = threadIdx.x;
    float s = 0.0f;
    for (int r = tid; r < NV; r += 256) {
        float m = INFINITY;
#pragma unroll
        for (int nt = 0; nt < 4; nt++)
            m = fminf(m, rowpart[((size_t)(b * 4 + nt)) * NV + r]);
        s += m * (1.0f / NV);
    }
    for (int c = tid; c < NL; c += 256) {
        float m = INFINITY;
#pragma unroll
        for (int mt = 0; mt < 8; mt++)
            m = fminf(m, colpart[((size_t)(b * 8 + mt)) * NL + c]);
        s += m * (1.0f / NL);
    }
    __shared__ float red[4];
#pragma unroll
    for (int off = 32; off > 0; off >>= 1) s += __shfl_down(s, off);
    if ((tid & 63) == 0) red[tid >> 6] = s;
    __syncthreads();
    if (tid == 0) out[b] = red[0] + red[1] + red[2] + red[3];
}

// ============================================================================
extern "C" void kernel_launch(void* const* d_in, const int* in_sizes, int n_in,
                              void* d_out, int out_size, void* d_ws, size_t ws_size,
                              hipStream_t stream) {
    const float* video = (const float*)d_in[0];  // [64,1024,512] fp32
    const float* lang = (const float*)d_in[1];   // [64,512,512] fp32
    float* out = (float*)d_out;                  // [64]

    float* rowpart = (float*)d_ws;                      // 64*4*1024 floats (1 MB)
    float* colpart = rowpart + (size_t)BATCH * 4 * NV;  // 64*8*512 floats (1 MB)

    fused_distmin_kernel<<<dim3(2048), 256, 0, stream>>>(video, lang, rowpart, colpart);
    reduce2_kernel<<<BATCH, 256, 0, stream>>>(rowpart, colpart, out);
}

// Round 5
// 69.236 us; speedup vs baseline: 1.2877x; 1.2877x over previous
//
#include <hip/hip_runtime.h>
#include <math.h>

#define BATCH 64
#define NV 1024
#define NL 512
#define DIM 512
#define TMM 256
#define TNN 128
#define BK 32
#define NKT (DIM / BK)   // 16 K-iterations

typedef __bf16 bf16x8 __attribute__((ext_vector_type(8)));
typedef __bf16 bf16x4 __attribute__((ext_vector_type(4)));
typedef float f32x4 __attribute__((ext_vector_type(4)));

// =====================================================================
// Fused kernel: fp32 load -> (norms, bf16 convert) -> LDS -> MFMA GEMM
// -> distance epilogue -> row/col min partials.
// grid = 1024 (XCD-chunked to (b, mt, nt)), block = 512 (8 waves, 4x2
// of 64x64 wave tiles over a 256x128 output tile).
// R3-proven loop shape: single staging regset, one barrier per K-iter.
// =====================================================================
__global__ __launch_bounds__(512, 2) void fused_distmin_kernel(
    const float* __restrict__ video, const float* __restrict__ lang,
    float* __restrict__ rowpart, float* __restrict__ colpart) {
    // Octet-major LDS: slab o in [0,4) holds k = [o*8, o*8+8) for all rows,
    // 16B per (o,row) entry. b128 reads and b64 writes are bank-even.
    __shared__ __align__(16) ushort AsU[2][4][TMM][8];  // 32 KB
    __shared__ __align__(16) ushort BsU[2][4][TNN][8];  // 16 KB
    __shared__ float anrm[TMM], bnrm[TNN];
    __shared__ float rowred[2][TMM], colred[4][TNN];

    // XCD-aware chunked swizzle: nwg = 1024 = 8 XCD * 128; each XCD gets
    // 8 complete batches (16 blocks/batch).
    const int wg = ((blockIdx.x & 7) << 7) | (blockIdx.x >> 3);
    const int b = wg >> 4;          // 64 batches
    const int mt = (wg >> 2) & 3;   // 4 video row-blocks of 256
    const int nt = wg & 3;          // 4 lang col-blocks of 128

    const int tid = threadIdx.x;
    const int lane = tid & 63;
    const int w = tid >> 6;         // 0..7
    const int wrow = w >> 1;        // 0..3
    const int wcol = w & 1;         // 0..1
    const int lr = lane & 15;
    const int g = lane >> 4;        // k-octet for fragment reads

    // staging geometry: srow in [0,64), skq = k-quad in [0,8)
    const int srow = tid >> 3;
    const int skq = tid & 7;
    const int o_sl = skq >> 1;      // LDS slab
    const int half = skq & 1;       // 8B half of the 16B entry

    const float* Ath = video + ((size_t)b * NV + (size_t)mt * TMM + srow) * DIM + skq * 4;
    const float* Bth = lang + ((size_t)b * NL + (size_t)nt * TNN + srow) * DIM + skq * 4;

    float nA[4] = {0.f, 0.f, 0.f, 0.f};   // rows srow + 64t
    float nB[2] = {0.f, 0.f};             // rows srow, srow+64

    f32x4 acc[4][4];
#pragma unroll
    for (int i = 0; i < 4; i++)
#pragma unroll
        for (int j = 0; j < 4; j++) acc[i][j] = (f32x4){0.f, 0.f, 0.f, 0.f};

    float4 va[4], vb[2];

    auto load_chunk = [&](int k0) {
#pragma unroll
        for (int t = 0; t < 4; ++t)
            va[t] = *(const float4*)(Ath + (size_t)t * 64 * DIM + k0);
#pragma unroll
        for (int t = 0; t < 2; ++t)
            vb[t] = *(const float4*)(Bth + (size_t)t * 64 * DIM + k0);
    };
    auto write_chunk = [&](int buf) {
#pragma unroll
        for (int t = 0; t < 4; ++t) {
            float4 v = va[t];
            nA[t] += v.x * v.x + v.y * v.y + v.z * v.z + v.w * v.w;
            bf16x4 p = {(__bf16)v.x, (__bf16)v.y, (__bf16)v.z, (__bf16)v.w};
            *(bf16x4*)&AsU[buf][o_sl][srow + 64 * t][half * 4] = p;
        }
#pragma unroll
        for (int t = 0; t < 2; ++t) {
            float4 u = vb[t];
            nB[t] += u.x * u.x + u.y * u.y + u.z * u.z + u.w * u.w;
            bf16x4 q = {(__bf16)u.x, (__bf16)u.y, (__bf16)u.z, (__bf16)u.w};
            *(bf16x4*)&BsU[buf][o_sl][srow + 64 * t][half * 4] = q;
        }
    };

    // prologue: stage k-tile 0 into buf 0
    load_chunk(0);
    write_chunk(0);
    __syncthreads();

    for (int kt = 0; kt < NKT; ++kt) {
        const int cur = kt & 1;
        const bool more = (kt + 1) < NKT;
        if (more) load_chunk((kt + 1) * BK);   // next-tile loads issued early

        bf16x8 av[4], bv[4];
#pragma unroll
        for (int fr = 0; fr < 4; ++fr)
            av[fr] = *(const bf16x8*)&AsU[cur][g][wrow * 64 + fr * 16 + lr][0];
#pragma unroll
        for (int fc = 0; fc < 4; ++fc)
            bv[fc] = *(const bf16x8*)&BsU[cur][g][wcol * 64 + fc * 16 + lr][0];
#pragma unroll
        for (int fr = 0; fr < 4; ++fr)
#pragma unroll
            for (int fc = 0; fc < 4; ++fc)
                acc[fr][fc] = __builtin_amdgcn_mfma_f32_16x16x32_bf16(
                    av[fr], bv[fc], acc[fr][fc], 0, 0, 0);

        if (more) write_chunk(cur ^ 1);        // cvt + norm-fma + ds_write after MFMA
        __syncthreads();
    }

    // ---- norms: reduce partials across the 8 threads sharing each row ----
#pragma unroll
    for (int s = 1; s < 8; s <<= 1) {
#pragma unroll
        for (int t = 0; t < 4; ++t) nA[t] += __shfl_xor(nA[t], s);
#pragma unroll
        for (int t = 0; t < 2; ++t) nB[t] += __shfl_xor(nB[t], s);
    }
    if ((tid & 7) == 0) {
#pragma unroll
        for (int t = 0; t < 4; ++t) anrm[srow + 64 * t] = nA[t];
#pragma unroll
        for (int t = 0; t < 2; ++t) bnrm[srow + 64 * t] = nB[t];
    }
    __syncthreads();

    // ---- epilogue: d = |v|^2 - 2 dot + |l|^2, row/col mins ----
    const int rgrp = (lane >> 4) * 4;
    float anorm[4][4];
#pragma unroll
    for (int fr = 0; fr < 4; ++fr)
#pragma unroll
        for (int r = 0; r < 4; ++r)
            anorm[fr][r] = anrm[wrow * 64 + fr * 16 + rgrp + r];
    float bnorm[4];
#pragma unroll
    for (int fc = 0; fc < 4; ++fc)
        bnorm[fc] = bnrm[wcol * 64 + fc * 16 + lr];

    float rmin[4][4];
    float cmin[4];
#pragma unroll
    for (int fr = 0; fr < 4; ++fr)
#pragma unroll
        for (int r = 0; r < 4; ++r) rmin[fr][r] = INFINITY;
#pragma unroll
    for (int fc = 0; fc < 4; ++fc) cmin[fc] = INFINITY;

#pragma unroll
    for (int fr = 0; fr < 4; ++fr)
#pragma unroll
        for (int fc = 0; fc < 4; ++fc)
#pragma unroll
            for (int r = 0; r < 4; ++r) {
                float d = anorm[fr][r] - 2.0f * acc[fr][fc][r] + bnorm[fc];
                rmin[fr][r] = fminf(rmin[fr][r], d);
                cmin[fc] = fminf(cmin[fc], d);
            }

#pragma unroll
    for (int fr = 0; fr < 4; ++fr)
#pragma unroll
        for (int r = 0; r < 4; ++r) {
#pragma unroll
            for (int off = 1; off < 16; off <<= 1)
                rmin[fr][r] = fminf(rmin[fr][r], __shfl_xor(rmin[fr][r], off));
        }
#pragma unroll
    for (int fc = 0; fc < 4; ++fc) {
#pragma unroll
        for (int off = 16; off < 64; off <<= 1)
            cmin[fc] = fminf(cmin[fc], __shfl_xor(cmin[fc], off));
    }

    if ((lane & 15) == 0) {
#pragma unroll
        for (int fr = 0; fr < 4; ++fr)
#pragma unroll
            for (int r = 0; r < 4; ++r)
                rowred[wcol][wrow * 64 + fr * 16 + rgrp + r] = rmin[fr][r];
    }
    if (lane < 16) {
#pragma unroll
        for (int fc = 0; fc < 4; ++fc)
            colred[wrow][wcol * 64 + fc * 16 + lane] = cmin[fc];
    }
    __syncthreads();
    if (tid < TMM) {
        rowpart[((size_t)(b * 4 + nt)) * NV + mt * TMM + tid] =
            fminf(rowred[0][tid], rowred[1][tid]);
    } else if (tid < TMM + TNN) {
        int c2 = tid - TMM;
        colpart[((size_t)(b * 4 + mt)) * NL + nt * TNN + c2] =
            fminf(fminf(colred[0][c2], colred[1][c2]),
                  fminf(colred[2][c2], colred[3][c2]));
    }
}

// ---------------- final reduce ----------------------------------------------
__global__ __launch_bounds__(256) void reduce2_kernel(
    const float* __restrict__ rowpart, const float* __restrict__ colpart,
    float* __restrict__ out) {
    int b = blockIdx.x;
    int tid = threadIdx.x;
    float s = 0.0f;
    for (int r = tid; r < NV; r += 256) {
        float m = INFINITY;
#pragma unroll
        for (int nt = 0; nt < 4; nt++)
            m = fminf(m, rowpart[((size_t)(b * 4 + nt)) * NV + r]);
        s += m * (1.0f / NV);
    }
    for (int c = tid; c < NL; c += 256) {
        float m = INFINITY;
#pragma unroll
        for (int mt = 0; mt < 4; mt++)
            m = fminf(m, colpart[((size_t)(b * 4 + mt)) * NL + c]);
        s += m * (1.0f / NL);
    }
    __shared__ float red[4];
#pragma unroll
    for (int off = 32; off > 0; off >>= 1) s += __shfl_down(s, off);
    if ((tid & 63) == 0) red[tid >> 6] = s;
    __syncthreads();
    if (tid == 0) out[b] = red[0] + red[1] + red[2] + red[3];
}

// ============================================================================
extern "C" void kernel_launch(void* const* d_in, const int* in_sizes, int n_in,
                              void* d_out, int out_size, void* d_ws, size_t ws_size,
                              hipStream_t stream) {
    const float* video = (const float*)d_in[0];  // [64,1024,512] fp32
    const float* lang = (const float*)d_in[1];   // [64,512,512] fp32
    float* out = (float*)d_out;                  // [64]

    float* rowpart = (float*)d_ws;                      // 64*4*1024 floats (1 MB)
    float* colpart = rowpart + (size_t)BATCH * 4 * NV;  // 64*4*512 floats (0.5 MB)

    fused_distmin_kernel<<<dim3(1024), 512, 0, stream>>>(video, lang, rowpart, colpart);
    reduce2_kernel<<<BATCH, 256, 0, stream>>>(rowpart, colpart, out);
}